// Round 2
// baseline (671.593 us; speedup 1.0000x reference)
//
#include <hip/hip_runtime.h>
#include <stdint.h>

#define TT 128
#define BSZ 512
#define HID 512
#define KDIM 512
#define BH (BSZ*HID)   // 262144 neurons

// ---------------- fp32 tiled GEMM: C[m][n] = sum_k A[m][k] * W[n][k] ----------------
// A row-major [Mc,512], W row-major [512,512] (both K-contiguous), C fp32 [Mc,512].
// 128x128 block tile, 256 threads, 8x8 microtile, BK=16, LDS stored transposed [k][m].
__global__ __launch_bounds__(256) void gemm_f32(
    const float* __restrict__ A, const float* __restrict__ W, float* __restrict__ C) {
  __shared__ float As[16][132];   // [k][m], row stride 132 floats = 528 B (16B-aligned)
  __shared__ float Bs[16][132];   // [k][n]
  const int t  = threadIdx.x;
  const int m0 = blockIdx.y * 128;
  const int n0 = blockIdx.x * 128;
  const int tx = t & 15;          // n microtile index
  const int ty = t >> 4;          // m microtile index

  float acc[8][8];
  #pragma unroll
  for (int i = 0; i < 8; ++i)
    #pragma unroll
    for (int j = 0; j < 8; ++j) acc[i][j] = 0.f;

  const int r0 = t >> 2;          // staging row 0..63 (row+64 on second load)
  const int kg = t & 3;           // k-group (float4 within 16-wide k tile)

  for (int k0 = 0; k0 < KDIM; k0 += 16) {
    // global loads first (hide latency), then barrier, then LDS transpose-write
    const float4 a0 = *(const float4*)&A[(size_t)(m0 + r0)      * KDIM + k0 + kg*4];
    const float4 w0 = *(const float4*)&W[(size_t)(n0 + r0)      * KDIM + k0 + kg*4];
    const float4 a1 = *(const float4*)&A[(size_t)(m0 + r0 + 64) * KDIM + k0 + kg*4];
    const float4 w1 = *(const float4*)&W[(size_t)(n0 + r0 + 64) * KDIM + k0 + kg*4];
    __syncthreads();  // previous iteration's readers done before overwrite
    As[kg*4+0][r0] = a0.x; As[kg*4+1][r0] = a0.y; As[kg*4+2][r0] = a0.z; As[kg*4+3][r0] = a0.w;
    Bs[kg*4+0][r0] = w0.x; Bs[kg*4+1][r0] = w0.y; Bs[kg*4+2][r0] = w0.z; Bs[kg*4+3][r0] = w0.w;
    As[kg*4+0][r0+64] = a1.x; As[kg*4+1][r0+64] = a1.y; As[kg*4+2][r0+64] = a1.z; As[kg*4+3][r0+64] = a1.w;
    Bs[kg*4+0][r0+64] = w1.x; Bs[kg*4+1][r0+64] = w1.y; Bs[kg*4+2][r0+64] = w1.z; Bs[kg*4+3][r0+64] = w1.w;
    __syncthreads();

    #pragma unroll
    for (int kk = 0; kk < 16; ++kk) {
      const float4 xa0 = *(const float4*)&As[kk][ty*8];
      const float4 xa1 = *(const float4*)&As[kk][ty*8+4];
      const float4 xb0 = *(const float4*)&Bs[kk][tx*8];
      const float4 xb1 = *(const float4*)&Bs[kk][tx*8+4];
      const float a[8] = {xa0.x,xa0.y,xa0.z,xa0.w,xa1.x,xa1.y,xa1.z,xa1.w};
      const float b[8] = {xb0.x,xb0.y,xb0.z,xb0.w,xb1.x,xb1.y,xb1.z,xb1.w};
      #pragma unroll
      for (int i = 0; i < 8; ++i)
        #pragma unroll
        for (int j = 0; j < 8; ++j)
          acc[i][j] = __builtin_fmaf(a[i], b[j], acc[i][j]);
    }
  }

  #pragma unroll
  for (int i = 0; i < 8; ++i) {
    float4 v0 = {acc[i][0], acc[i][1], acc[i][2], acc[i][3]};
    float4 v1 = {acc[i][4], acc[i][5], acc[i][6], acc[i][7]};
    float* cp = C + (size_t)(m0 + ty*8 + i) * HID + n0 + tx*8;
    *(float4*)cp = v0;
    *(float4*)(cp + 4) = v1;
  }
}

// ---------------- LIF scan (bit-identical to np fp32 reference given xp) ----------------
// One thread per neuron. xp: fp32 [tc,B,H] (no bias). outp: fp32 avg spikes (layer 3).
// vstate: fp32 [4,BH] region = output-1 region of d_out, doubles as chunk-carry storage;
// last chunk overwrites it with final-t avg_v (the actual output 1).
__global__ __launch_bounds__(256) void lif_scan(
    const float* __restrict__ xp, const float* __restrict__ bias,
    float* __restrict__ outp, float* __restrict__ vstate,
    int tc, int first, int last) {
  const int idx = blockIdx.x * 256 + threadIdx.x;
  const float bh = bias[idx & (HID - 1)];
  float v[4];
  if (first) {
    #pragma unroll
    for (int l = 0; l < 4; ++l) v[l] = 0.f;
  } else {
    #pragma unroll
    for (int l = 0; l < 4; ++l) v[l] = vstate[(size_t)l * BH + idx];
  }
  float av[4] = {0.f, 0.f, 0.f, 0.f};
  const float* p = xp + idx;
  float* op = outp + idx;
  for (int t = 0; t < tc; ++t) {
    float y = p[0] + bh;            // layer-0 input (single fp32 rounding, matches ref)
    float as3 = 0.f;
    #pragma unroll
    for (int l = 0; l < 4; ++l) {
      float vv = v[l];
      float accv = 0.f, accs = 0.f;
      #pragma unroll
      for (int k = 0; k < 4; ++k) {
        const float d = y - vv;                       // round(inp - v)
        vv = __builtin_fmaf(d, 0.5f, vv);             // round(v + d*0.5): d*0.5 exact
        const float spk = (vv >= 1.0f) ? 1.0f : 0.0f; // v-1>=0 <=> v>=1 (exact)
        vv -= spk;                                    // soft reset
        accv += vv;
        accs += spk;
      }
      v[l] = vv;
      const float a = accv * 0.25f;                   // exact /4
      av[l] = a;
      y = a;                                          // next layer consumes avg_v
      as3 = accs;
    }
    *op = as3 * 0.25f;
    p += BH; op += BH;
  }
  if (last) {
    #pragma unroll
    for (int l = 0; l < 4; ++l) vstate[(size_t)l * BH + idx] = av[l];
  } else {
    #pragma unroll
    for (int l = 0; l < 4; ++l) vstate[(size_t)l * BH + idx] = v[l];
  }
}

extern "C" void kernel_launch(void* const* d_in, const int* in_sizes, int n_in,
                              void* d_out, int out_size, void* d_ws, size_t ws_size,
                              hipStream_t stream) {
  const float* x = (const float*)d_in[0];   // [128,512,512] fp32
  const float* W = (const float*)d_in[1];   // [512,512] fp32
  const float* b = (const float*)d_in[2];   // [512] fp32
  float* out    = (float*)d_out;            // [128,512,512] avg spikes (fp32)
  float* states = out + (size_t)TT * BH;    // [4,512,512] final avg_v; also chunk-carry v

  // workspace holds only the fp32 xp chunk: tc MiB
  int tc = TT;
  while (tc > 1 && (size_t)tc * BH * 4ull > ws_size) tc >>= 1;
  float* xp = (float*)d_ws;
  const int nc = TT / tc;

  for (int c = 0; c < nc; ++c) {
    hipLaunchKernelGGL(gemm_f32, dim3(HID / 128, tc * BSZ / 128), dim3(256), 0, stream,
                       x + (size_t)c * tc * BH, W, xp);
    hipLaunchKernelGGL(lif_scan, dim3(BH / 256), dim3(256), 0, stream,
                       xp, b, out + (size_t)c * tc * BH, states,
                       tc, c == 0 ? 1 : 0, c == nc - 1 ? 1 : 0);
  }
}

// Round 5
// 645.031 us; speedup vs baseline: 1.0412x; 1.0412x over previous
//
#include <hip/hip_runtime.h>
#include <stdint.h>

#define TT 128
#define BSZ 512
#define HID 512
#define KDIM 512
#define BH (BSZ*HID)   // 262144 neurons

// ---------------- fp32 tiled GEMM: C[m][n] = sum_k A[m][k] * W[n][k] + bias[n] --------
// A row-major [Mc,512], W row-major [512,512] (both K-contiguous), C fp32 [Mc,512].
// 128x128 block tile, 256 threads, 8x8 microtile, BK=16, LDS stored transposed [k][m].
// NUMERICS CONTRACT (bit-exact vs np ref, absmax 0.0 in R2): per output element the
// reduction is ONE sequential fma chain over k ascending, fp32. Do not reorder/split.
__global__ __launch_bounds__(256) void gemm_f32(
    const float* __restrict__ A, const float* __restrict__ W,
    const float* __restrict__ bias, float* __restrict__ C) {
  __shared__ float As[16][132];   // [k][m], row stride 132 floats (bank shift 4/row)
  __shared__ float Bs[16][132];   // [k][n]
  const int t  = threadIdx.x;
  const int m0 = blockIdx.y * 128;
  const int n0 = blockIdx.x * 128;
  const int tx = t & 15;          // n group: columns {tx*4..+3} and {64+tx*4..+3}
  const int ty = t >> 4;          // m group: rows ty*8..ty*8+7
  const int r0 = t >> 2;          // staging row 0..63 (and +64)
  const int kg = t & 3;           // k float4 group within 16-wide k tile

  float acc[8][8];
  #pragma unroll
  for (int i = 0; i < 8; ++i)
    #pragma unroll
    for (int j = 0; j < 8; ++j) acc[i][j] = 0.f;

  const float* Ap = A + (size_t)(m0 + r0) * KDIM + kg * 4;
  const float* Wp = W + (size_t)(n0 + r0) * KDIM + kg * 4;

  // software pipeline: tile k0 lives in regs before the k0 loop body runs
  float4 a0 = *(const float4*)Ap;
  float4 w0 = *(const float4*)Wp;
  float4 a1 = *(const float4*)(Ap + (size_t)64 * KDIM);
  float4 w1 = *(const float4*)(Wp + (size_t)64 * KDIM);

  for (int k0 = 0; k0 < KDIM; k0 += 16) {
    __syncthreads();   // previous iteration's readers done before overwrite (no-op first)
    As[kg*4+0][r0]    = a0.x; As[kg*4+1][r0]    = a0.y; As[kg*4+2][r0]    = a0.z; As[kg*4+3][r0]    = a0.w;
    Bs[kg*4+0][r0]    = w0.x; Bs[kg*4+1][r0]    = w0.y; Bs[kg*4+2][r0]    = w0.z; Bs[kg*4+3][r0]    = w0.w;
    As[kg*4+0][r0+64] = a1.x; As[kg*4+1][r0+64] = a1.y; As[kg*4+2][r0+64] = a1.z; As[kg*4+3][r0+64] = a1.w;
    Bs[kg*4+0][r0+64] = w1.x; Bs[kg*4+1][r0+64] = w1.y; Bs[kg*4+2][r0+64] = w1.z; Bs[kg*4+3][r0+64] = w1.w;
    __syncthreads();

    if (k0 + 16 < KDIM) {   // prefetch next tile; latency hidden under the fma block
      a0 = *(const float4*)(Ap + k0 + 16);
      w0 = *(const float4*)(Wp + k0 + 16);
      a1 = *(const float4*)(Ap + (size_t)64 * KDIM + k0 + 16);
      w1 = *(const float4*)(Wp + (size_t)64 * KDIM + k0 + 16);
    }

    #pragma unroll
    for (int kk = 0; kk < 16; ++kk) {
      const float4 xa0 = *(const float4*)&As[kk][ty*8];        // broadcast, conflict-free
      const float4 xa1 = *(const float4*)&As[kk][ty*8 + 4];
      const float4 xb0 = *(const float4*)&Bs[kk][tx*4];        // stride-4: 2-way = free
      const float4 xb1 = *(const float4*)&Bs[kk][64 + tx*4];
      const float a[8] = {xa0.x,xa0.y,xa0.z,xa0.w,xa1.x,xa1.y,xa1.z,xa1.w};
      const float b[8] = {xb0.x,xb0.y,xb0.z,xb0.w,xb1.x,xb1.y,xb1.z,xb1.w};
      #pragma unroll
      for (int i = 0; i < 8; ++i)
        #pragma unroll
        for (int j = 0; j < 8; ++j)
          acc[i][j] = __builtin_fmaf(a[i], b[j], acc[i][j]);
    }
  }

  // epilogue: + bias (ref adds b once to xp — identical), coalesced float4 stores
  const float4 bv0 = *(const float4*)&bias[n0 + tx*4];
  const float4 bv1 = *(const float4*)&bias[n0 + 64 + tx*4];
  #pragma unroll
  for (int i = 0; i < 8; ++i) {
    const float4 v0 = {acc[i][0] + bv0.x, acc[i][1] + bv0.y, acc[i][2] + bv0.z, acc[i][3] + bv0.w};
    const float4 v1 = {acc[i][4] + bv1.x, acc[i][5] + bv1.y, acc[i][6] + bv1.z, acc[i][7] + bv1.w};
    float* cp = C + (size_t)(m0 + ty*8 + i) * HID + n0;
    *(float4*)(cp + tx*4)      = v0;
    *(float4*)(cp + 64 + tx*4) = v1;
  }
}

// ---------------- LIF scan (bit-identical to np fp32 reference given xp) ----------------
__device__ __forceinline__ float lif_step(float y, float v[4], float av[4]) {
  float as3 = 0.f;
  #pragma unroll
  for (int l = 0; l < 4; ++l) {
    float vv = v[l];
    float accv = 0.f, accs = 0.f;
    #pragma unroll
    for (int k = 0; k < 4; ++k) {
      const float d = y - vv;                        // round(inp - v)
      vv = __builtin_fmaf(d, 0.5f, vv);              // round(v + d*0.5): d*0.5 exact
      const float spk = (vv >= 1.0f) ? 1.0f : 0.0f;  // v-1>=0 <=> v>=1 (exact)
      vv -= spk;                                     // soft reset
      accv += vv;
      accs += spk;
    }
    v[l] = vv;
    const float a = accv * 0.25f;                    // exact /4
    av[l] = a;
    y = a;                                           // next layer consumes avg_v
    as3 = accs;
  }
  return as3;
}

// One thread per neuron. xp: fp32 [tc,B,H] (bias already included). outp: fp32 avg spikes
// (layer 3). vstate = output-1 region, doubles as chunk-carry; last chunk writes final avg_v.
__global__ __launch_bounds__(256) void lif_scan(
    const float* __restrict__ xp, float* __restrict__ outp, float* __restrict__ vstate,
    int tc, int first, int last) {
  const int idx = blockIdx.x * 256 + threadIdx.x;
  float v[4];
  if (first) {
    #pragma unroll
    for (int l = 0; l < 4; ++l) v[l] = 0.f;
  } else {
    #pragma unroll
    for (int l = 0; l < 4; ++l) v[l] = vstate[(size_t)l * BH + idx];
  }
  float av[4] = {0.f, 0.f, 0.f, 0.f};
  const float* p = xp + idx;
  float* op = outp + idx;

  float cur = *p;                        // prefetched input for step t
  for (int t = 0; t < tc - 1; ++t) {
    const float nxt = p[BH];             // prefetch t+1 before the ~224-cycle compute
    const float as3 = lif_step(cur, v, av);
    *op = as3 * 0.25f;
    cur = nxt; p += BH; op += BH;
  }
  const float as3 = lif_step(cur, v, av);  // peeled last step (no prefetch)
  *op = as3 * 0.25f;

  if (last) {
    #pragma unroll
    for (int l = 0; l < 4; ++l) vstate[(size_t)l * BH + idx] = av[l];
  } else {
    #pragma unroll
    for (int l = 0; l < 4; ++l) vstate[(size_t)l * BH + idx] = v[l];
  }
}

extern "C" void kernel_launch(void* const* d_in, const int* in_sizes, int n_in,
                              void* d_out, int out_size, void* d_ws, size_t ws_size,
                              hipStream_t stream) {
  const float* x = (const float*)d_in[0];   // [128,512,512] fp32
  const float* W = (const float*)d_in[1];   // [512,512] fp32
  const float* b = (const float*)d_in[2];   // [512] fp32
  float* out    = (float*)d_out;            // [128,512,512] avg spikes (fp32)
  float* states = out + (size_t)TT * BH;    // [4,512,512] final avg_v; also chunk-carry v

  int tc = TT;                              // xp chunk: tc MiB of ws
  while (tc > 1 && (size_t)tc * BH * 4ull > ws_size) tc >>= 1;
  float* xp = (float*)d_ws;
  const int nc = TT / tc;

  for (int c = 0; c < nc; ++c) {
    hipLaunchKernelGGL(gemm_f32, dim3(HID / 128, tc * BSZ / 128), dim3(256), 0, stream,
                       x + (size_t)c * tc * BH, W, b, xp);
    hipLaunchKernelGGL(lif_scan, dim3(BH / 256), dim3(256), 0, stream,
                       xp, out + (size_t)c * tc * BH, states,
                       tc, c == 0 ? 1 : 0, c == nc - 1 ? 1 : 0);
  }
}

// Round 6
// 615.872 us; speedup vs baseline: 1.0905x; 1.0473x over previous
//
#include <hip/hip_runtime.h>
#include <stdint.h>

#define TT 128
#define BSZ 512
#define HID 512
#define KDIM 512
#define BH (BSZ*HID)   // 262144 neurons

// ---------------- fp32 tiled GEMM: C[m][n] = sum_k A[m][k] * W[n][k] + bias[n] --------
// 128x128 block tile, 256 threads, 8x8 microtile, BK=16, DOUBLE-BUFFERED LDS (one
// barrier per k-tile), LDS stored transposed [k][m] with stride 132.
// NUMERICS CONTRACT (bit-exact vs np ref, absmax 0.0 in R2/R5): per output element the
// reduction is ONE sequential fma chain over k ascending, fp32. Do not reorder/split.
__global__ __launch_bounds__(256) void gemm_f32(
    const float* __restrict__ A, const float* __restrict__ W,
    const float* __restrict__ bias, float* __restrict__ C) {
  __shared__ float As[2][16][132];   // 2 buffers: [k][m], +4/row bank shift
  __shared__ float Bs[2][16][132];
  const int t  = threadIdx.x;
  const int m0 = blockIdx.y * 128;
  const int n0 = blockIdx.x * 128;
  const int tx = t & 15;          // n group: columns {tx*4..+3} and {64+tx*4..+3}
  const int ty = t >> 4;          // m group: rows ty*8..ty*8+7
  const int r0 = t >> 2;          // staging row 0..63 (and +64)
  const int kg = t & 3;           // k float4 group within 16-wide k tile

  float acc[8][8];
  #pragma unroll
  for (int i = 0; i < 8; ++i)
    #pragma unroll
    for (int j = 0; j < 8; ++j) acc[i][j] = 0.f;

  const float* Ap = A + (size_t)(m0 + r0) * KDIM + kg * 4;
  const float* Wp = W + (size_t)(n0 + r0) * KDIM + kg * 4;

  float4 a0 = *(const float4*)Ap;
  float4 w0 = *(const float4*)Wp;
  float4 a1 = *(const float4*)(Ap + (size_t)64 * KDIM);
  float4 w1 = *(const float4*)(Wp + (size_t)64 * KDIM);

  // stage tile 0 into buffer 0
  #define STAGE(BUF) do { \
    As[BUF][kg*4+0][r0]    = a0.x; As[BUF][kg*4+1][r0]    = a0.y; \
    As[BUF][kg*4+2][r0]    = a0.z; As[BUF][kg*4+3][r0]    = a0.w; \
    Bs[BUF][kg*4+0][r0]    = w0.x; Bs[BUF][kg*4+1][r0]    = w0.y; \
    Bs[BUF][kg*4+2][r0]    = w0.z; Bs[BUF][kg*4+3][r0]    = w0.w; \
    As[BUF][kg*4+0][r0+64] = a1.x; As[BUF][kg*4+1][r0+64] = a1.y; \
    As[BUF][kg*4+2][r0+64] = a1.z; As[BUF][kg*4+3][r0+64] = a1.w; \
    Bs[BUF][kg*4+0][r0+64] = w1.x; Bs[BUF][kg*4+1][r0+64] = w1.y; \
    Bs[BUF][kg*4+2][r0+64] = w1.z; Bs[BUF][kg*4+3][r0+64] = w1.w; \
  } while (0)

  STAGE(0);

  int cur = 0;
  for (int k0 = 0; k0 < KDIM; k0 += 16) {
    // Single barrier per tile. Drains lgkmcnt -> (a) buf[cur] writes visible,
    // (b) previous iteration's ds_reads of buf[cur^1] complete, so staging into
    // buf[cur^1] below is safe.
    __syncthreads();
    const bool more = (k0 + 16 < KDIM);
    if (more) {   // global prefetch of next tile; latency hidden under the fma block
      a0 = *(const float4*)(Ap + k0 + 16);
      w0 = *(const float4*)(Wp + k0 + 16);
      a1 = *(const float4*)(Ap + (size_t)64 * KDIM + k0 + 16);
      w1 = *(const float4*)(Wp + (size_t)64 * KDIM + k0 + 16);
    }

    #pragma unroll
    for (int kk = 0; kk < 16; ++kk) {
      const float4 xa0 = *(const float4*)&As[cur][kk][ty*8];      // broadcast
      const float4 xa1 = *(const float4*)&As[cur][kk][ty*8 + 4];
      const float4 xb0 = *(const float4*)&Bs[cur][kk][tx*4];      // stride-4: 2-way, free
      const float4 xb1 = *(const float4*)&Bs[cur][kk][64 + tx*4];
      const float a[8] = {xa0.x,xa0.y,xa0.z,xa0.w,xa1.x,xa1.y,xa1.z,xa1.w};
      const float b[8] = {xb0.x,xb0.y,xb0.z,xb0.w,xb1.x,xb1.y,xb1.z,xb1.w};
      #pragma unroll
      for (int i = 0; i < 8; ++i)
        #pragma unroll
        for (int j = 0; j < 8; ++j)
          acc[i][j] = __builtin_fmaf(a[i], b[j], acc[i][j]);
    }

    if (more) {
      const int nb = cur ^ 1;
      STAGE(nb);      // overlaps other waves' compute; protected by next barrier
    }
    cur ^= 1;
  }
  #undef STAGE

  // epilogue: + bias (ref adds b once to xp — identical), coalesced float4 stores
  const float4 bv0 = *(const float4*)&bias[n0 + tx*4];
  const float4 bv1 = *(const float4*)&bias[n0 + 64 + tx*4];
  #pragma unroll
  for (int i = 0; i < 8; ++i) {
    const float4 v0 = {acc[i][0] + bv0.x, acc[i][1] + bv0.y, acc[i][2] + bv0.z, acc[i][3] + bv0.w};
    const float4 v1 = {acc[i][4] + bv1.x, acc[i][5] + bv1.y, acc[i][6] + bv1.z, acc[i][7] + bv1.w};
    float* cp = C + (size_t)(m0 + ty*8 + i) * HID + n0;
    *(float4*)(cp + tx*4)      = v0;
    *(float4*)(cp + 64 + tx*4) = v1;
  }
}

// ---------------- LIF scan (bit-identical to np fp32 reference given xp) ----------------
__device__ __forceinline__ float lif_step(float y, float v[4], float av[4]) {
  float as3 = 0.f;
  #pragma unroll
  for (int l = 0; l < 4; ++l) {
    float vv = v[l];
    float accv = 0.f, accs = 0.f;
    #pragma unroll
    for (int k = 0; k < 4; ++k) {
      const float d = y - vv;                        // round(inp - v)
      vv = __builtin_fmaf(d, 0.5f, vv);              // round(v + d*0.5): d*0.5 exact
      const float spk = (vv >= 1.0f) ? 1.0f : 0.0f;  // v-1>=0 <=> v>=1 (exact)
      vv -= spk;                                     // soft reset
      accv += vv;
      accs += spk;
    }
    v[l] = vv;
    const float a = accv * 0.25f;                    // exact /4
    av[l] = a;
    y = a;                                           // next layer consumes avg_v
    as3 = accs;
  }
  return as3;
}

// One thread per neuron. xp loads are INDEPENDENT across t (precomputed array), so we
// run a 4-deep prefetch: 4 loads in flight cover ~900-cycle HBM latency with ~960
// issue-cycles of LIF compute per group.
__global__ __launch_bounds__(256) void lif_scan(
    const float* __restrict__ xp, float* __restrict__ outp, float* __restrict__ vstate,
    int tc, int first, int last) {
  const int idx = blockIdx.x * 256 + threadIdx.x;
  float v[4];
  if (first) {
    #pragma unroll
    for (int l = 0; l < 4; ++l) v[l] = 0.f;
  } else {
    #pragma unroll
    for (int l = 0; l < 4; ++l) v[l] = vstate[(size_t)l * BH + idx];
  }
  float av[4] = {0.f, 0.f, 0.f, 0.f};
  const float* p = xp + idx;
  float* op = outp + idx;

  if ((tc & 3) == 0 && tc >= 8) {
    float curb[4];
    #pragma unroll
    for (int i = 0; i < 4; ++i) curb[i] = p[(size_t)i * BH];
    for (int t = 0; t + 4 < tc; t += 4) {
      float nxtb[4];
      #pragma unroll
      for (int i = 0; i < 4; ++i) nxtb[i] = p[(size_t)(i + 4) * BH];  // issued pre-compute
      #pragma unroll
      for (int i = 0; i < 4; ++i) {
        const float as3 = lif_step(curb[i], v, av);
        op[(size_t)i * BH] = as3 * 0.25f;
      }
      #pragma unroll
      for (int i = 0; i < 4; ++i) curb[i] = nxtb[i];
      p += 4 * BH; op += 4 * BH;
    }
    #pragma unroll
    for (int i = 0; i < 4; ++i) {    // tail group, already in registers
      const float as3 = lif_step(curb[i], v, av);
      op[(size_t)i * BH] = as3 * 0.25f;
    }
  } else {
    for (int t = 0; t < tc; ++t) {
      const float as3 = lif_step(p[0], v, av);
      *op = as3 * 0.25f;
      p += BH; op += BH;
    }
  }

  if (last) {
    #pragma unroll
    for (int l = 0; l < 4; ++l) vstate[(size_t)l * BH + idx] = av[l];
  } else {
    #pragma unroll
    for (int l = 0; l < 4; ++l) vstate[(size_t)l * BH + idx] = v[l];
  }
}

extern "C" void kernel_launch(void* const* d_in, const int* in_sizes, int n_in,
                              void* d_out, int out_size, void* d_ws, size_t ws_size,
                              hipStream_t stream) {
  const float* x = (const float*)d_in[0];   // [128,512,512] fp32
  const float* W = (const float*)d_in[1];   // [512,512] fp32
  const float* b = (const float*)d_in[2];   // [512] fp32
  float* out    = (float*)d_out;            // [128,512,512] avg spikes (fp32)
  float* states = out + (size_t)TT * BH;    // [4,512,512] final avg_v; also chunk-carry v

  int tc = TT;                              // xp chunk: tc MiB of ws
  while (tc > 1 && (size_t)tc * BH * 4ull > ws_size) tc >>= 1;
  float* xp = (float*)d_ws;
  const int nc = TT / tc;

  for (int c = 0; c < nc; ++c) {
    hipLaunchKernelGGL(gemm_f32, dim3(HID / 128, tc * BSZ / 128), dim3(256), 0, stream,
                       x + (size_t)c * tc * BH, W, b, xp);
    hipLaunchKernelGGL(lif_scan, dim3(BH / 256), dim3(256), 0, stream,
                       xp, out + (size_t)c * tc * BH, states,
                       tc, c == 0 ? 1 : 0, c == nc - 1 ? 1 : 0);
  }
}